// Round 23
// baseline (122.906 us; speedup 1.0000x reference)
//
#include <hip/hip_runtime.h>
#include <hip/hip_bf16.h>

// Problem constants
#define DIMD 1024
#define NH   16
#define NKV  4
#define HDIM 64
#define WINSZ 512
#define BB   4
#define TT   2048
#define MROWS (BB*TT)      // 8192
#define NQKV 1536

typedef __attribute__((ext_vector_type(8))) short short8;
typedef __attribute__((ext_vector_type(4))) float f32x4;

static __device__ __forceinline__ short f2bf(float f) {
  __hip_bfloat16 h = __float2bfloat16(f);
  return __builtin_bit_cast(short, h);
}
static __device__ __forceinline__ float bf2f(short s) {
  return __bfloat162float(__builtin_bit_cast(__hip_bfloat16, s));
}
static __device__ __forceinline__ unsigned pk2(float a, float b) {
  unsigned lo = (unsigned short)f2bf(a);
  unsigned hi = (unsigned short)f2bf(b);
  return lo | (hi << 16);
}

static __device__ __forceinline__ void gld_lds16(const void* g, void* l) {
  __builtin_amdgcn_global_load_lds(
      (const __attribute__((address_space(1))) unsigned int*)g,
      (__attribute__((address_space(3))) unsigned int*)l, 16, 0, 0);
}

// DPP rotate-right within each 16-lane row
template<int N>
static __device__ __forceinline__ float dpp_ror(float x) {
  return __builtin_bit_cast(float, __builtin_amdgcn_update_dpp(
      0, __builtin_bit_cast(int, x), 0x120 + N, 0xF, 0xF, true));
}

// ---------------------------------------------------------------------------
// 1) f32 -> bf16 conversion for x, wq|wk|wv (packed), wo.  Unit = 4 floats.
__global__ __launch_bounds__(256) void cvt_all_kernel(
    const float* __restrict__ x, const float* __restrict__ wq,
    const float* __restrict__ wk, const float* __restrict__ wv,
    const float* __restrict__ wo,
    short* __restrict__ xb, short* __restrict__ wqkvb, short* __restrict__ wob) {
  size_t u = (size_t)blockIdx.x * 256 + threadIdx.x;
  const float* src; short* dst;
  if (u < 2097152)                   { src = x;  dst = xb; }
  else if ((u -= 2097152) < 262144)  { src = wq; dst = wqkvb; }
  else if ((u -= 262144) < 65536)    { src = wk; dst = wqkvb + 1024*1024; }
  else if ((u -= 65536) < 65536)     { src = wv; dst = wqkvb + 1280*1024; }
  else { u -= 65536;                   src = wo; dst = wob; }
  float4 v = ((const float4*)src)[u];
  short4 o;
  o.x = f2bf(v.x); o.y = f2bf(v.y); o.z = f2bf(v.z); o.w = f2bf(v.w);
  ((short4*)dst)[u] = o;
}

// ---------------------------------------------------------------------------
// 2) GEMM  C[M][N] = A[M][K] * B[N][K]^T   (bf16 in, bf16 or f32 out)
#define BMT 128
#define BNT 128
#define BKT 64

template<bool OUT_BF16>
__global__ __launch_bounds__(256) void gemm_bt(
    const short* __restrict__ A, const short* __restrict__ Bw,
    void* __restrict__ Cout, int M, int N, int K) {
  __shared__ __align__(16) short As[BMT*BKT];
  __shared__ __align__(16) short Bs[BNT*BKT];

  int nwg  = gridDim.x;
  int orig = blockIdx.x;
  int wg   = (orig & 7) * (nwg >> 3) + (orig >> 3);   // XCD swizzle (nwg%8==0)
  int tiles_n = N / BNT;
  int m0 = (wg / tiles_n) * BMT;
  int n0 = (wg % tiles_n) * BNT;

  int tid = threadIdx.x;
  int lane = tid & 63, wv = tid >> 6;
  int l15 = lane & 15, lg = lane >> 4;
  int wr = wv >> 1, wc = wv & 1;

  f32x4 acc[4][4] = {};

  for (int k0 = 0; k0 < K; k0 += BKT) {
    __syncthreads();
    const char* Abase = (const char*)(A + (size_t)m0 * K + k0);
    const char* Bbase = (const char*)(Bw + (size_t)n0 * K + k0);
#pragma unroll
    for (int i = 0; i < 4; ++i) {
      int idx = i * 256 + tid;
      int row = idx >> 3;
      int cb  = (idx & 7) << 4;
      int scb = cb ^ ((row & 7) << 4);
      gld_lds16(Abase + (size_t)row * (K * 2) + scb,
                (char*)As + ((i * 256 + wv * 64) << 4));
      gld_lds16(Bbase + (size_t)row * (K * 2) + scb,
                (char*)Bs + ((i * 256 + wv * 64) << 4));
    }
    __syncthreads();

#pragma unroll
    for (int kk = 0; kk < 2; ++kk) {
      short8 af[4], bfr[4];
      int kb = (kk * 32 + lg * 8) * 2;
#pragma unroll
      for (int mi = 0; mi < 4; ++mi) {
        int row = wr * 64 + mi * 16 + l15;
        af[mi] = *(const short8*)((const char*)As + row * 128 + (kb ^ ((row & 7) << 4)));
      }
#pragma unroll
      for (int ni = 0; ni < 4; ++ni) {
        int row = wc * 64 + ni * 16 + l15;
        bfr[ni] = *(const short8*)((const char*)Bs + row * 128 + (kb ^ ((row & 7) << 4)));
      }
#pragma unroll
      for (int mi = 0; mi < 4; ++mi)
#pragma unroll
        for (int ni = 0; ni < 4; ++ni)
          acc[mi][ni] = __builtin_amdgcn_mfma_f32_16x16x32_bf16(af[mi], bfr[ni], acc[mi][ni], 0, 0, 0);
    }
  }

  int crow0 = m0 + wr * 64, ccol0 = n0 + wc * 64;
#pragma unroll
  for (int mi = 0; mi < 4; ++mi)
#pragma unroll
    for (int ni = 0; ni < 4; ++ni)
#pragma unroll
      for (int r = 0; r < 4; ++r) {
        int row = crow0 + mi * 16 + lg * 4 + r;
        int col = ccol0 + ni * 16 + l15;
        float v = acc[mi][ni][r];
        if (OUT_BF16) ((short*)Cout)[(size_t)row * N + col] = f2bf(v);
        else          ((float*)Cout)[(size_t)row * N + col] = v;
      }
}

// ---------------------------------------------------------------------------
// 3) FUSED qk_norm + vtrans.  Blocks [0,10240): RMSNorm on q/k heads.
//    Blocks [10240,10752): V transpose qkv cols [1280..1536) -> Vt.
__global__ __launch_bounds__(256) void norm_vtrans_kernel(
    const short* __restrict__ qkv, const float* __restrict__ qw,
    const float* __restrict__ kw, short* __restrict__ Qh,
    short* __restrict__ Kh, short* __restrict__ Vt) {
  __shared__ short tile[64][72];
  if (blockIdx.x < 10240) {
    unsigned gid = blockIdx.x * 16u + (threadIdx.x >> 4);
    int l = threadIdx.x & 15;
    unsigned row = gid / 20u;          // b*T + t
    int s = (int)(gid - row * 20u);    // head slot 0..19
    int b = row >> 11, t = row & 2047;
    bool isq = s < 16;
    int col = isq ? s * 64 : 1024 + (s - 16) * 64;
    const short* rp = qkv + (size_t)row * NQKV + col + l * 4;
    short4 v4 = *(const short4*)rp;
    float f0 = bf2f(v4.x), f1 = bf2f(v4.y), f2 = bf2f(v4.z), f3 = bf2f(v4.w);
    float ss = f0 * f0 + f1 * f1 + f2 * f2 + f3 * f3;
    ss += dpp_ror<1>(ss); ss += dpp_ror<2>(ss);
    ss += dpp_ror<4>(ss); ss += dpp_ror<8>(ss);
    float r = rsqrtf(ss * (1.0f / 64.0f) + 1e-6f);
    float4 w4 = *(const float4*)((isq ? qw : kw) + l * 4);
    short4 o;
    o.x = f2bf(f0 * r * w4.x); o.y = f2bf(f1 * r * w4.y);
    o.z = f2bf(f2 * r * w4.z); o.w = f2bf(f3 * r * w4.w);
    if (isq) *(short4*)(Qh + (((size_t)b * NH + s) * TT + t) * HDIM + l * 4) = o;
    else     *(short4*)(Kh + (((size_t)b * NKV + (s - 16)) * TT + t) * HDIM + l * 4) = o;
  } else {
    int vi = blockIdx.x - 10240;
    int tb = vi & 31, kv = (vi >> 5) & 3, b = vi >> 7;
    int tid = threadIdx.x;
#pragma unroll
    for (int i = 0; i < 2; ++i) {
      int idx = i * 256 + tid;
      int tr = idx >> 3;
      int c8 = (idx & 7) * 8;
      int t = tb * 64 + tr;
      const short* src = qkv + (size_t)(b * TT + t) * NQKV + 1280 + kv * 64 + c8;
      short8 v = *(const short8*)src;
#pragma unroll
      for (int j = 0; j < 8; ++j) tile[tr][c8 + j] = v[j];
    }
    __syncthreads();
#pragma unroll
    for (int i = 0; i < 2; ++i) {
      int idx = i * 256 + tid;
      int d = idx >> 3;
      int t8 = (idx & 7) * 8;
      short8 o;
#pragma unroll
      for (int j = 0; j < 8; ++j) o[j] = tile[t8 + j][d];
      short* dst = Vt + (((size_t)(b * NKV + kv) * HDIM) + d) * TT + tb * 64 + t8;
      *(short8*)dst = o;
    }
  }
}

// ---------------------------------------------------------------------------
// 5) Sliding-window causal flash attention (GQA).
//    BLOCK = (b, kvh, qh): 4 waves = the 4 q-heads of one GQA group sharing
//    the same 32-q window.  K and V tiles (8KB each) staged per block into
//    LDS (rule-21 XOR swizzle: linear dest, pre-swizzled src, swizzled read).
//    r23: REVERT to the r18 single-tile staging (best, 44.0us; r21's 2-tile
//    variant raised bank conflicts) + IN-WAVE PIPE OVERLAP: per-tile order is
//    softmax-A -> PV-A(MFMA) -> softmax-B -> PV-B so PV-A's MFMA executes
//    under softmax-B's VALU (separate pipes, m114).  Same ops, new order.
#define C1A 0.180336880f   // 0.125 * log2(e)
#define C2A 11.5415603f    // 8     * log2(e)

__global__ __launch_bounds__(256) void attn_kernel(
    const short* __restrict__ Qh, const short* __restrict__ Kh,
    const short* __restrict__ Vt, short* __restrict__ Y) {
  int wgid = blockIdx.x;
  int qh = wgid >> 4;                  // 0..63, SLOWEST (per-CU balance)
  int kvh = (wgid >> 2) & 3;
  int b = wgid & 3;
  int tid = threadIdx.x, lane = tid & 63, wv = tid >> 6;
  int l15 = lane & 15, lg = lane >> 4;
  int h = kvh * 4 + wv;                // this wave's q-head
  int q0 = qh * 32;
  const short* Qp = Qh + (((size_t)b * NH + h) * TT + q0) * HDIM;
  const char*  Kp = (const char*)(Kh + ((size_t)b * NKV + kvh) * TT * HDIM);
  const char*  Vp = (const char*)(Vt + ((size_t)b * NKV + kvh) * HDIM * TT);

  short8 aqA0 = *(const short8*)(Qp + l15 * HDIM + lg * 8);
  short8 aqA1 = *(const short8*)(Qp + l15 * HDIM + 32 + lg * 8);
  short8 aqB0 = *(const short8*)(Qp + (16 + l15) * HDIM + lg * 8);
  short8 aqB1 = *(const short8*)(Qp + (16 + l15) * HDIM + 32 + lg * 8);

  float lpA = 0.f, lpB = 0.f;          // lane-scalar partials (q = l15)
  f32x4 yA[4] = {}, yB[4] = {};

  // LDS: K 8192 + V 8192 + 4 x 4608 per-wave P scratch = 34816 B
  __shared__ __align__(16) char smem[34816];
  char* Kbuf = smem;
  char* Vbuf = smem + 8192;
  short* PA = (short*)(smem + 16384 + wv * 4608);
  short* PB = PA + 1152;

  int lo = q0 - (WINSZ - 1); if (lo < 0) lo = 0;
  int klo = lo & ~63;
  int nt = (q0 + 32 - klo + 63) >> 6;  // CEIL tile count

  int qiA = q0 + l15, qiB = qiA + 16;  // q index per lane (swapped layout)

  for (int t = 0; t < nt; ++t) {
    int kc = klo + t * 64;
    __syncthreads();                   // prior tile's LDS reads complete
    // ---- STAGE K and V tiles: wave wv stages rows wv*16..wv*16+15 of each
    //      (2 x 1KB per operand).  LDS dest linear; source pre-swizzled:
    //      LDS[rr][cb] = X[rr][cb ^ ((rr&7)<<4)]
#pragma unroll
    for (int r = 0; r < 2; ++r) {
      int rr = wv * 16 + r * 8 + (lane >> 3);
      int cb = (lane & 7) * 16;
      int scb = cb ^ ((rr & 7) << 4);
      gld_lds16(Kp + (size_t)(kc + rr) * 128 + scb,
                Kbuf + wv * 2048 + r * 1024);
      gld_lds16(Vp + (size_t)rr * (TT * 2) + kc * 2 + scb,
                Vbuf + wv * 2048 + r * 1024);
    }
    __syncthreads();                   // vmcnt(0) drain: staging complete

    int sw = (l15 & 7) << 4;
    // ---- K fragments from LDS (swizzled read)
    short8 bk0[4], bk1[4];
#pragma unroll
    for (int nc = 0; nc < 4; ++nc) {
      int rb = (nc * 16 + l15) * 128;
      bk0[nc] = *(const short8*)(Kbuf + rb + ((lg * 16) ^ sw));
      bk1[nc] = *(const short8*)(Kbuf + rb + ((lg * 16 + 64) ^ sw));
    }
    // ---- V fragments from LDS (same pattern)
    short8 bv0[4], bv1[4];
#pragma unroll
    for (int dt = 0; dt < 4; ++dt) {
      int rb = (dt * 16 + l15) * 128;
      bv0[dt] = *(const short8*)(Vbuf + rb + ((lg * 16) ^ sw));
      bv1[dt] = *(const short8*)(Vbuf + rb + ((lg * 16 + 64) ^ sw));
    }
    // ---- swapped QK^T: D[k][q] (both subtiles)
    f32x4 sA[4], sB[4];
    __builtin_amdgcn_s_setprio(1);
#pragma unroll
    for (int nc = 0; nc < 4; ++nc) {
      f32x4 zA = {}, zB = {};
      zA = __builtin_amdgcn_mfma_f32_16x16x32_bf16(bk0[nc], aqA0, zA, 0, 0, 0);
      zB = __builtin_amdgcn_mfma_f32_16x16x32_bf16(bk0[nc], aqB0, zB, 0, 0, 0);
      zA = __builtin_amdgcn_mfma_f32_16x16x32_bf16(bk1[nc], aqA1, zA, 0, 0, 0);
      zB = __builtin_amdgcn_mfma_f32_16x16x32_bf16(bk1[nc], aqB1, zB, 0, 0, 0);
      sA[nc] = zA; sB[nc] = zB;
    }
    __builtin_amdgcn_s_setprio(0);

    bool intA = (kc >= q0 - 496) && (kc + 63 <= q0);
    bool intB = (kc >= q0 - 480) && (kc + 63 <= q0 + 16);

    // ---- softmax-A + PA write
    if (intA) {
#pragma unroll
      for (int nc = 0; nc < 4; ++nc) {
        float pa0 = __builtin_amdgcn_exp2f(fmaf(sA[nc][0], C1A, -C2A));
        float pa1 = __builtin_amdgcn_exp2f(fmaf(sA[nc][1], C1A, -C2A));
        float pa2 = __builtin_amdgcn_exp2f(fmaf(sA[nc][2], C1A, -C2A));
        float pa3 = __builtin_amdgcn_exp2f(fmaf(sA[nc][3], C1A, -C2A));
        lpA += (pa0 + pa1) + (pa2 + pa3);
        *(uint2*)(PA + l15 * 72 + nc * 16 + lg * 4) = uint2{pk2(pa0, pa1), pk2(pa2, pa3)};
      }
    } else {
      int kjb = kc + lg * 4;
#pragma unroll
      for (int nc = 0; nc < 4; ++nc) {
        float pa[4];
#pragma unroll
        for (int r = 0; r < 4; ++r) {
          int kj = kjb + nc * 16 + r;
          bool okA = (kj <= qiA) && (qiA - kj < WINSZ);
          pa[r] = okA ? __builtin_amdgcn_exp2f(fmaf(sA[nc][r], C1A, -C2A)) : 0.f;
        }
        lpA += (pa[0] + pa[1]) + (pa[2] + pa[3]);
        *(uint2*)(PA + l15 * 72 + nc * 16 + lg * 4) = uint2{pk2(pa[0], pa[1]), pk2(pa[2], pa[3])};
      }
    }
    // ---- PV-A issued NOW: its MFMA runs under softmax-B's VALU
    short8 apA0 = *(const short8*)(PA + l15 * 72 + lg * 8);
    short8 apA1 = *(const short8*)(PA + l15 * 72 + 32 + lg * 8);
    __builtin_amdgcn_s_setprio(1);
#pragma unroll
    for (int dt = 0; dt < 4; ++dt) {
      yA[dt] = __builtin_amdgcn_mfma_f32_16x16x32_bf16(apA0, bv0[dt], yA[dt], 0, 0, 0);
      yA[dt] = __builtin_amdgcn_mfma_f32_16x16x32_bf16(apA1, bv1[dt], yA[dt], 0, 0, 0);
    }
    __builtin_amdgcn_s_setprio(0);
    // ---- softmax-B + PB write
    if (intB) {
#pragma unroll
      for (int nc = 0; nc < 4; ++nc) {
        float pb0 = __builtin_amdgcn_exp2f(fmaf(sB[nc][0], C1A, -C2A));
        float pb1 = __builtin_amdgcn_exp2f(fmaf(sB[nc][1], C1A, -C2A));
        float pb2 = __builtin_amdgcn_exp2f(fmaf(sB[nc][2], C1A, -C2A));
        float pb3 = __builtin_amdgcn_exp2f(fmaf(sB[nc][3], C1A, -C2A));
        lpB += (pb0 + pb1) + (pb2 + pb3);
        *(uint2*)(PB + l15 * 72 + nc * 16 + lg * 4) = uint2{pk2(pb0, pb1), pk2(pb2, pb3)};
      }
    } else {
      int kjb = kc + lg * 4;
#pragma unroll
      for (int nc = 0; nc < 4; ++nc) {
        float pb[4];
#pragma unroll
        for (int r = 0; r < 4; ++r) {
          int kj = kjb + nc * 16 + r;
          bool okB = (kj <= qiB) && (qiB - kj < WINSZ);
          pb[r] = okB ? __builtin_amdgcn_exp2f(fmaf(sB[nc][r], C1A, -C2A)) : 0.f;
        }
        lpB += (pb[0] + pb[1]) + (pb[2] + pb[3]);
        *(uint2*)(PB + l15 * 72 + nc * 16 + lg * 4) = uint2{pk2(pb[0], pb[1]), pk2(pb[2], pb[3])};
      }
    }
    // ---- PV-B
    short8 apB0 = *(const short8*)(PB + l15 * 72 + lg * 8);
    short8 apB1 = *(const short8*)(PB + l15 * 72 + 32 + lg * 8);
    __builtin_amdgcn_s_setprio(1);
#pragma unroll
    for (int dt = 0; dt < 4; ++dt) {
      yB[dt] = __builtin_amdgcn_mfma_f32_16x16x32_bf16(apB0, bv0[dt], yB[dt], 0, 0, 0);
      yB[dt] = __builtin_amdgcn_mfma_f32_16x16x32_bf16(apB1, bv1[dt], yB[dt], 0, 0, 0);
    }
    __builtin_amdgcn_s_setprio(0);
  }

  // ---- per-wave epilogue (wave owns its head completely; no combine)
  lpA += __shfl_xor(lpA, 16); lpA += __shfl_xor(lpA, 32);
  lpB += __shfl_xor(lpB, 16); lpB += __shfl_xor(lpB, 32);
  float invqA = 1.0f / lpA;            // q = l15
  float invqB = 1.0f / lpB;
#pragma unroll
  for (int r = 0; r < 4; ++r) {
    // redistribute: y rows are q = lg*4+r -> pull inv from lane (lg*4+r)
    float invA = __builtin_bit_cast(float, __builtin_amdgcn_ds_bpermute(
        (lg * 4 + r) << 2, __builtin_bit_cast(int, invqA)));
    float invB = __builtin_bit_cast(float, __builtin_amdgcn_ds_bpermute(
        (lg * 4 + r) << 2, __builtin_bit_cast(int, invqB)));
    int qiAo = q0 + lg * 4 + r, qiBo = qiAo + 16;
#pragma unroll
    for (int dt = 0; dt < 4; ++dt) {
      Y[((size_t)(b * TT + qiAo)) * DIMD + h * HDIM + dt * 16 + l15] = f2bf(yA[dt][r] * invA);
      Y[((size_t)(b * TT + qiBo)) * DIMD + h * HDIM + dt * 16 + l15] = f2bf(yB[dt][r] * invB);
    }
  }
}

// ---------------------------------------------------------------------------
extern "C" void kernel_launch(void* const* d_in, const int* in_sizes, int n_in,
                              void* d_out, int out_size, void* d_ws, size_t ws_size,
                              hipStream_t stream) {
  const float* x  = (const float*)d_in[0];
  const float* wq = (const float*)d_in[1];
  const float* wk = (const float*)d_in[2];
  const float* wv = (const float*)d_in[3];
  const float* wo = (const float*)d_in[4];
  const float* qw = (const float*)d_in[5];
  const float* kw = (const float*)d_in[6];

  char* ws = (char*)d_ws;
  short* xb    = (short*)(ws + 0);            // 16 MB  [8192][1024] bf16
  short* wqkvb = (short*)(ws + 16777216);     // 3 MB   [1536][1024]
  short* wob   = (short*)(ws + 19922944);     // 2 MB   [1024][1024]
  short* qkv   = (short*)(ws + 22020096);     // 24 MB  [8192][1536]
  short* Qh    = (short*)(ws + 47185920);     // 16 MB  [B][H][T][64]
  short* Kh    = (short*)(ws + 63963136);     // 4 MB   [B][KV][T][64]
  short* Vt    = (short*)(ws + 68157440);     // 4 MB   [B][KV][64][T]
  short* Y     = xb;                          // alias: xb dead after QKV GEMM
  float* outp  = (float*)d_out;

  cvt_all_kernel<<<10752, 256, 0, stream>>>(x, wq, wk, wv, wo, xb, wqkvb, wob);
  gemm_bt<true><<<dim3(64 * 12), 256, 0, stream>>>(xb, wqkvb, (void*)qkv, MROWS, NQKV, DIMD);
  norm_vtrans_kernel<<<10752, 256, 0, stream>>>(qkv, qw, kw, Qh, Kh, Vt);
  attn_kernel<<<1024, 256, 0, stream>>>(Qh, Kh, Vt, Y);
  gemm_bt<false><<<dim3(64 * 8), 256, 0, stream>>>(Y, wob, (void*)outp, MROWS, DIMD, DIMD);
}

// Round 24
// 120.369 us; speedup vs baseline: 1.0211x; 1.0211x over previous
//
#include <hip/hip_runtime.h>
#include <hip/hip_bf16.h>

// Problem constants
#define DIMD 1024
#define NH   16
#define NKV  4
#define HDIM 64
#define WINSZ 512
#define BB   4
#define TT   2048
#define MROWS (BB*TT)      // 8192
#define NQKV 1536

typedef __attribute__((ext_vector_type(8))) short short8;
typedef __attribute__((ext_vector_type(4))) float f32x4;

static __device__ __forceinline__ short f2bf(float f) {
  __hip_bfloat16 h = __float2bfloat16(f);
  return __builtin_bit_cast(short, h);
}
static __device__ __forceinline__ float bf2f(short s) {
  return __bfloat162float(__builtin_bit_cast(__hip_bfloat16, s));
}
static __device__ __forceinline__ unsigned pk2(float a, float b) {
  unsigned lo = (unsigned short)f2bf(a);
  unsigned hi = (unsigned short)f2bf(b);
  return lo | (hi << 16);
}

static __device__ __forceinline__ void gld_lds16(const void* g, void* l) {
  __builtin_amdgcn_global_load_lds(
      (const __attribute__((address_space(1))) unsigned int*)g,
      (__attribute__((address_space(3))) unsigned int*)l, 16, 0, 0);
}

// DPP rotate-right within each 16-lane row
template<int N>
static __device__ __forceinline__ float dpp_ror(float x) {
  return __builtin_bit_cast(float, __builtin_amdgcn_update_dpp(
      0, __builtin_bit_cast(int, x), 0x120 + N, 0xF, 0xF, true));
}

// ---------------------------------------------------------------------------
// 1) f32 -> bf16 conversion for x, wq|wk|wv (packed), wo.  Unit = 4 floats.
__global__ __launch_bounds__(256) void cvt_all_kernel(
    const float* __restrict__ x, const float* __restrict__ wq,
    const float* __restrict__ wk, const float* __restrict__ wv,
    const float* __restrict__ wo,
    short* __restrict__ xb, short* __restrict__ wqkvb, short* __restrict__ wob) {
  size_t u = (size_t)blockIdx.x * 256 + threadIdx.x;
  const float* src; short* dst;
  if (u < 2097152)                   { src = x;  dst = xb; }
  else if ((u -= 2097152) < 262144)  { src = wq; dst = wqkvb; }
  else if ((u -= 262144) < 65536)    { src = wk; dst = wqkvb + 1024*1024; }
  else if ((u -= 65536) < 65536)     { src = wv; dst = wqkvb + 1280*1024; }
  else { u -= 65536;                   src = wo; dst = wob; }
  float4 v = ((const float4*)src)[u];
  short4 o;
  o.x = f2bf(v.x); o.y = f2bf(v.y); o.z = f2bf(v.z); o.w = f2bf(v.w);
  ((short4*)dst)[u] = o;
}

// ---------------------------------------------------------------------------
// 2) GEMM  C[M][N] = A[M][K] * B[N][K]^T   (bf16 in, bf16 or f32 out)
#define BMT 128
#define BNT 128
#define BKT 64

template<bool OUT_BF16>
__global__ __launch_bounds__(256) void gemm_bt(
    const short* __restrict__ A, const short* __restrict__ Bw,
    void* __restrict__ Cout, int M, int N, int K) {
  __shared__ __align__(16) short As[BMT*BKT];
  __shared__ __align__(16) short Bs[BNT*BKT];

  int nwg  = gridDim.x;
  int orig = blockIdx.x;
  int wg   = (orig & 7) * (nwg >> 3) + (orig >> 3);   // XCD swizzle (nwg%8==0)
  int tiles_n = N / BNT;
  int m0 = (wg / tiles_n) * BMT;
  int n0 = (wg % tiles_n) * BNT;

  int tid = threadIdx.x;
  int lane = tid & 63, wv = tid >> 6;
  int l15 = lane & 15, lg = lane >> 4;
  int wr = wv >> 1, wc = wv & 1;

  f32x4 acc[4][4] = {};

  for (int k0 = 0; k0 < K; k0 += BKT) {
    __syncthreads();
    const char* Abase = (const char*)(A + (size_t)m0 * K + k0);
    const char* Bbase = (const char*)(Bw + (size_t)n0 * K + k0);
#pragma unroll
    for (int i = 0; i < 4; ++i) {
      int idx = i * 256 + tid;
      int row = idx >> 3;
      int cb  = (idx & 7) << 4;
      int scb = cb ^ ((row & 7) << 4);
      gld_lds16(Abase + (size_t)row * (K * 2) + scb,
                (char*)As + ((i * 256 + wv * 64) << 4));
      gld_lds16(Bbase + (size_t)row * (K * 2) + scb,
                (char*)Bs + ((i * 256 + wv * 64) << 4));
    }
    __syncthreads();

#pragma unroll
    for (int kk = 0; kk < 2; ++kk) {
      short8 af[4], bfr[4];
      int kb = (kk * 32 + lg * 8) * 2;
#pragma unroll
      for (int mi = 0; mi < 4; ++mi) {
        int row = wr * 64 + mi * 16 + l15;
        af[mi] = *(const short8*)((const char*)As + row * 128 + (kb ^ ((row & 7) << 4)));
      }
#pragma unroll
      for (int ni = 0; ni < 4; ++ni) {
        int row = wc * 64 + ni * 16 + l15;
        bfr[ni] = *(const short8*)((const char*)Bs + row * 128 + (kb ^ ((row & 7) << 4)));
      }
#pragma unroll
      for (int mi = 0; mi < 4; ++mi)
#pragma unroll
        for (int ni = 0; ni < 4; ++ni)
          acc[mi][ni] = __builtin_amdgcn_mfma_f32_16x16x32_bf16(af[mi], bfr[ni], acc[mi][ni], 0, 0, 0);
    }
  }

  int crow0 = m0 + wr * 64, ccol0 = n0 + wc * 64;
#pragma unroll
  for (int mi = 0; mi < 4; ++mi)
#pragma unroll
    for (int ni = 0; ni < 4; ++ni)
#pragma unroll
      for (int r = 0; r < 4; ++r) {
        int row = crow0 + mi * 16 + lg * 4 + r;
        int col = ccol0 + ni * 16 + l15;
        float v = acc[mi][ni][r];
        if (OUT_BF16) ((short*)Cout)[(size_t)row * N + col] = f2bf(v);
        else          ((float*)Cout)[(size_t)row * N + col] = v;
      }
}

// ---------------------------------------------------------------------------
// 3) FUSED qk_norm + vtrans.  Blocks [0,10240): RMSNorm on q/k heads.
//    Blocks [10240,10752): V transpose qkv cols [1280..1536) -> Vt.
__global__ __launch_bounds__(256) void norm_vtrans_kernel(
    const short* __restrict__ qkv, const float* __restrict__ qw,
    const float* __restrict__ kw, short* __restrict__ Qh,
    short* __restrict__ Kh, short* __restrict__ Vt) {
  __shared__ short tile[64][72];
  if (blockIdx.x < 10240) {
    unsigned gid = blockIdx.x * 16u + (threadIdx.x >> 4);
    int l = threadIdx.x & 15;
    unsigned row = gid / 20u;          // b*T + t
    int s = (int)(gid - row * 20u);    // head slot 0..19
    int b = row >> 11, t = row & 2047;
    bool isq = s < 16;
    int col = isq ? s * 64 : 1024 + (s - 16) * 64;
    const short* rp = qkv + (size_t)row * NQKV + col + l * 4;
    short4 v4 = *(const short4*)rp;
    float f0 = bf2f(v4.x), f1 = bf2f(v4.y), f2 = bf2f(v4.z), f3 = bf2f(v4.w);
    float ss = f0 * f0 + f1 * f1 + f2 * f2 + f3 * f3;
    ss += dpp_ror<1>(ss); ss += dpp_ror<2>(ss);
    ss += dpp_ror<4>(ss); ss += dpp_ror<8>(ss);
    float r = rsqrtf(ss * (1.0f / 64.0f) + 1e-6f);
    float4 w4 = *(const float4*)((isq ? qw : kw) + l * 4);
    short4 o;
    o.x = f2bf(f0 * r * w4.x); o.y = f2bf(f1 * r * w4.y);
    o.z = f2bf(f2 * r * w4.z); o.w = f2bf(f3 * r * w4.w);
    if (isq) *(short4*)(Qh + (((size_t)b * NH + s) * TT + t) * HDIM + l * 4) = o;
    else     *(short4*)(Kh + (((size_t)b * NKV + (s - 16)) * TT + t) * HDIM + l * 4) = o;
  } else {
    int vi = blockIdx.x - 10240;
    int tb = vi & 31, kv = (vi >> 5) & 3, b = vi >> 7;
    int tid = threadIdx.x;
#pragma unroll
    for (int i = 0; i < 2; ++i) {
      int idx = i * 256 + tid;
      int tr = idx >> 3;
      int c8 = (idx & 7) * 8;
      int t = tb * 64 + tr;
      const short* src = qkv + (size_t)(b * TT + t) * NQKV + 1280 + kv * 64 + c8;
      short8 v = *(const short8*)src;
#pragma unroll
      for (int j = 0; j < 8; ++j) tile[tr][c8 + j] = v[j];
    }
    __syncthreads();
#pragma unroll
    for (int i = 0; i < 2; ++i) {
      int idx = i * 256 + tid;
      int d = idx >> 3;
      int t8 = (idx & 7) * 8;
      short8 o;
#pragma unroll
      for (int j = 0; j < 8; ++j) o[j] = tile[t8 + j][d];
      short* dst = Vt + (((size_t)(b * NKV + kv) * HDIM) + d) * TT + tb * 64 + t8;
      *(short8*)dst = o;
    }
  }
}

// ---------------------------------------------------------------------------
// 5) Sliding-window causal flash attention (GQA).  r18 structure (best: 44us).
//    BLOCK = (b, kvh, qh): 4 waves = the 4 q-heads of one GQA group sharing
//    the same 32-q window.  BOTH K and V tiles (8KB each) staged per block
//    into LDS via global_load_lds (4 waves cooperative) with rule-21 XOR
//    swizzle (linear LDS dest, pre-swizzled global source, swizzled read).
//    Swapped QK^T (P[k][q] k-major/lane), fixed-max softmax, setprio MFMA.
#define C1A 0.180336880f   // 0.125 * log2(e)
#define C2A 11.5415603f    // 8     * log2(e)

__global__ __launch_bounds__(256) void attn_kernel(
    const short* __restrict__ Qh, const short* __restrict__ Kh,
    const short* __restrict__ Vt, short* __restrict__ Y) {
  int wgid = blockIdx.x;
  int qh = wgid >> 4;                  // 0..63, SLOWEST (per-CU balance)
  int kvh = (wgid >> 2) & 3;
  int b = wgid & 3;
  int tid = threadIdx.x, lane = tid & 63, wv = tid >> 6;
  int l15 = lane & 15, lg = lane >> 4;
  int h = kvh * 4 + wv;                // this wave's q-head
  int q0 = qh * 32;
  const short* Qp = Qh + (((size_t)b * NH + h) * TT + q0) * HDIM;
  const char*  Kp = (const char*)(Kh + ((size_t)b * NKV + kvh) * TT * HDIM);
  const char*  Vp = (const char*)(Vt + ((size_t)b * NKV + kvh) * HDIM * TT);

  short8 aqA0 = *(const short8*)(Qp + l15 * HDIM + lg * 8);
  short8 aqA1 = *(const short8*)(Qp + l15 * HDIM + 32 + lg * 8);
  short8 aqB0 = *(const short8*)(Qp + (16 + l15) * HDIM + lg * 8);
  short8 aqB1 = *(const short8*)(Qp + (16 + l15) * HDIM + 32 + lg * 8);

  float lpA = 0.f, lpB = 0.f;          // lane-scalar partials (q = l15)
  f32x4 yA[4] = {}, yB[4] = {};

  // LDS: K 8192 + V 8192 + 4 x 4608 per-wave P scratch = 34816 B
  __shared__ __align__(16) char smem[34816];
  char* Kbuf = smem;
  char* Vbuf = smem + 8192;
  short* PA = (short*)(smem + 16384 + wv * 4608);
  short* PB = PA + 1152;

  int lo = q0 - (WINSZ - 1); if (lo < 0) lo = 0;
  int klo = lo & ~63;
  int nt = (q0 + 32 - klo + 63) >> 6;  // CEIL tile count

  int qiA = q0 + l15, qiB = qiA + 16;  // q index per lane (swapped layout)

  for (int t = 0; t < nt; ++t) {
    int kc = klo + t * 64;
    __syncthreads();                   // prior tile's LDS reads complete
    // ---- STAGE K and V tiles: wave wv stages rows wv*16..wv*16+15 of each
    //      (2 x 1KB per operand).  LDS dest linear; source pre-swizzled:
    //      LDS[rr][cb] = X[rr][cb ^ ((rr&7)<<4)]
#pragma unroll
    for (int r = 0; r < 2; ++r) {
      int rr = wv * 16 + r * 8 + (lane >> 3);
      int cb = (lane & 7) * 16;
      int scb = cb ^ ((rr & 7) << 4);
      gld_lds16(Kp + (size_t)(kc + rr) * 128 + scb,
                Kbuf + wv * 2048 + r * 1024);
      gld_lds16(Vp + (size_t)rr * (TT * 2) + kc * 2 + scb,
                Vbuf + wv * 2048 + r * 1024);
    }
    __syncthreads();                   // vmcnt(0) drain: staging complete

    int sw = (l15 & 7) << 4;
    // ---- K fragments from LDS (swizzled read: conflict-free)
    short8 bk0[4], bk1[4];
#pragma unroll
    for (int nc = 0; nc < 4; ++nc) {
      int rb = (nc * 16 + l15) * 128;
      bk0[nc] = *(const short8*)(Kbuf + rb + ((lg * 16) ^ sw));
      bk1[nc] = *(const short8*)(Kbuf + rb + ((lg * 16 + 64) ^ sw));
    }
    // ---- V fragments from LDS (same pattern)
    short8 bv0[4], bv1[4];
#pragma unroll
    for (int dt = 0; dt < 4; ++dt) {
      int rb = (dt * 16 + l15) * 128;
      bv0[dt] = *(const short8*)(Vbuf + rb + ((lg * 16) ^ sw));
      bv1[dt] = *(const short8*)(Vbuf + rb + ((lg * 16 + 64) ^ sw));
    }
    // ---- swapped QK^T: D[k][q]
    f32x4 sA[4], sB[4];
    __builtin_amdgcn_s_setprio(1);
#pragma unroll
    for (int nc = 0; nc < 4; ++nc) {
      f32x4 zA = {}, zB = {};
      zA = __builtin_amdgcn_mfma_f32_16x16x32_bf16(bk0[nc], aqA0, zA, 0, 0, 0);
      zB = __builtin_amdgcn_mfma_f32_16x16x32_bf16(bk0[nc], aqB0, zB, 0, 0, 0);
      zA = __builtin_amdgcn_mfma_f32_16x16x32_bf16(bk1[nc], aqA1, zA, 0, 0, 0);
      zB = __builtin_amdgcn_mfma_f32_16x16x32_bf16(bk1[nc], aqB1, zB, 0, 0, 0);
      sA[nc] = zA; sB[nc] = zB;
    }
    __builtin_amdgcn_s_setprio(0);
    // ---- fixed-max softmax, pack, vector LDS write (k-major per lane)
    bool intA = (kc >= q0 - 496) && (kc + 63 <= q0);
    bool intB = (kc >= q0 - 480) && (kc + 63 <= q0 + 16);
    if (intA && intB) {
#pragma unroll
      for (int nc = 0; nc < 4; ++nc) {
        float pa0 = __builtin_amdgcn_exp2f(fmaf(sA[nc][0], C1A, -C2A));
        float pa1 = __builtin_amdgcn_exp2f(fmaf(sA[nc][1], C1A, -C2A));
        float pa2 = __builtin_amdgcn_exp2f(fmaf(sA[nc][2], C1A, -C2A));
        float pa3 = __builtin_amdgcn_exp2f(fmaf(sA[nc][3], C1A, -C2A));
        float pb0 = __builtin_amdgcn_exp2f(fmaf(sB[nc][0], C1A, -C2A));
        float pb1 = __builtin_amdgcn_exp2f(fmaf(sB[nc][1], C1A, -C2A));
        float pb2 = __builtin_amdgcn_exp2f(fmaf(sB[nc][2], C1A, -C2A));
        float pb3 = __builtin_amdgcn_exp2f(fmaf(sB[nc][3], C1A, -C2A));
        lpA += (pa0 + pa1) + (pa2 + pa3);
        lpB += (pb0 + pb1) + (pb2 + pb3);
        *(uint2*)(PA + l15 * 72 + nc * 16 + lg * 4) = uint2{pk2(pa0, pa1), pk2(pa2, pa3)};
        *(uint2*)(PB + l15 * 72 + nc * 16 + lg * 4) = uint2{pk2(pb0, pb1), pk2(pb2, pb3)};
      }
    } else {
      int kjb = kc + lg * 4;
#pragma unroll
      for (int nc = 0; nc < 4; ++nc) {
        float pa[4], pb[4];
#pragma unroll
        for (int r = 0; r < 4; ++r) {
          int kj = kjb + nc * 16 + r;
          bool okA = (kj <= qiA) && (qiA - kj < WINSZ);
          bool okB = (kj <= qiB) && (qiB - kj < WINSZ);
          pa[r] = okA ? __builtin_amdgcn_exp2f(fmaf(sA[nc][r], C1A, -C2A)) : 0.f;
          pb[r] = okB ? __builtin_amdgcn_exp2f(fmaf(sB[nc][r], C1A, -C2A)) : 0.f;
        }
        lpA += (pa[0] + pa[1]) + (pa[2] + pa[3]);
        lpB += (pb[0] + pb[1]) + (pb[2] + pb[3]);
        *(uint2*)(PA + l15 * 72 + nc * 16 + lg * 4) = uint2{pk2(pa[0], pa[1]), pk2(pa[2], pa[3])};
        *(uint2*)(PB + l15 * 72 + nc * 16 + lg * 4) = uint2{pk2(pb[0], pb[1]), pk2(pb[2], pb[3])};
      }
    }
    // ---- PV A-fragments (per-wave LDS region, no barrier)
    short8 apA0 = *(const short8*)(PA + l15 * 72 + lg * 8);
    short8 apA1 = *(const short8*)(PA + l15 * 72 + 32 + lg * 8);
    short8 apB0 = *(const short8*)(PB + l15 * 72 + lg * 8);
    short8 apB1 = *(const short8*)(PB + l15 * 72 + 32 + lg * 8);
    __builtin_amdgcn_s_setprio(1);
#pragma unroll
    for (int dt = 0; dt < 4; ++dt) {
      yA[dt] = __builtin_amdgcn_mfma_f32_16x16x32_bf16(apA0, bv0[dt], yA[dt], 0, 0, 0);
      yB[dt] = __builtin_amdgcn_mfma_f32_16x16x32_bf16(apB0, bv0[dt], yB[dt], 0, 0, 0);
      yA[dt] = __builtin_amdgcn_mfma_f32_16x16x32_bf16(apA1, bv1[dt], yA[dt], 0, 0, 0);
      yB[dt] = __builtin_amdgcn_mfma_f32_16x16x32_bf16(apB1, bv1[dt], yB[dt], 0, 0, 0);
    }
    __builtin_amdgcn_s_setprio(0);
  }

  // ---- per-wave epilogue (wave owns its head completely; no combine)
  lpA += __shfl_xor(lpA, 16); lpA += __shfl_xor(lpA, 32);
  lpB += __shfl_xor(lpB, 16); lpB += __shfl_xor(lpB, 32);
  float invqA = 1.0f / lpA;            // q = l15
  float invqB = 1.0f / lpB;
#pragma unroll
  for (int r = 0; r < 4; ++r) {
    // redistribute: y rows are q = lg*4+r -> pull inv from lane (lg*4+r)
    float invA = __builtin_bit_cast(float, __builtin_amdgcn_ds_bpermute(
        (lg * 4 + r) << 2, __builtin_bit_cast(int, invqA)));
    float invB = __builtin_bit_cast(float, __builtin_amdgcn_ds_bpermute(
        (lg * 4 + r) << 2, __builtin_bit_cast(int, invqB)));
    int qiAo = q0 + lg * 4 + r, qiBo = qiAo + 16;
#pragma unroll
    for (int dt = 0; dt < 4; ++dt) {
      Y[((size_t)(b * TT + qiAo)) * DIMD + h * HDIM + dt * 16 + l15] = f2bf(yA[dt][r] * invA);
      Y[((size_t)(b * TT + qiBo)) * DIMD + h * HDIM + dt * 16 + l15] = f2bf(yB[dt][r] * invB);
    }
  }
}

// ---------------------------------------------------------------------------
extern "C" void kernel_launch(void* const* d_in, const int* in_sizes, int n_in,
                              void* d_out, int out_size, void* d_ws, size_t ws_size,
                              hipStream_t stream) {
  const float* x  = (const float*)d_in[0];
  const float* wq = (const float*)d_in[1];
  const float* wk = (const float*)d_in[2];
  const float* wv = (const float*)d_in[3];
  const float* wo = (const float*)d_in[4];
  const float* qw = (const float*)d_in[5];
  const float* kw = (const float*)d_in[6];

  char* ws = (char*)d_ws;
  short* xb    = (short*)(ws + 0);            // 16 MB  [8192][1024] bf16
  short* wqkvb = (short*)(ws + 16777216);     // 3 MB   [1536][1024]
  short* wob   = (short*)(ws + 19922944);     // 2 MB   [1024][1024]
  short* qkv   = (short*)(ws + 22020096);     // 24 MB  [8192][1536]
  short* Qh    = (short*)(ws + 47185920);     // 16 MB  [B][H][T][64]
  short* Kh    = (short*)(ws + 63963136);     // 4 MB   [B][KV][T][64]
  short* Vt    = (short*)(ws + 68157440);     // 4 MB   [B][KV][64][T]
  short* Y     = xb;                          // alias: xb dead after QKV GEMM
  float* outp  = (float*)d_out;

  cvt_all_kernel<<<10752, 256, 0, stream>>>(x, wq, wk, wv, wo, xb, wqkvb, wob);
  gemm_bt<true><<<dim3(64 * 12), 256, 0, stream>>>(xb, wqkvb, (void*)qkv, MROWS, NQKV, DIMD);
  norm_vtrans_kernel<<<10752, 256, 0, stream>>>(qkv, qw, kw, Qh, Kh, Vt);
  attn_kernel<<<1024, 256, 0, stream>>>(Qh, Kh, Vt, Y);
  gemm_bt<false><<<dim3(64 * 8), 256, 0, stream>>>(Y, wob, (void*)outp, MROWS, DIMD, DIMD);
}

// Round 25
// 118.251 us; speedup vs baseline: 1.0394x; 1.0179x over previous
//
#include <hip/hip_runtime.h>
#include <hip/hip_bf16.h>

// Problem constants
#define DIMD 1024
#define NH   16
#define NKV  4
#define HDIM 64
#define WINSZ 512
#define BB   4
#define TT   2048
#define MROWS (BB*TT)      // 8192
#define NQKV 1536

typedef __attribute__((ext_vector_type(8))) short short8;
typedef __attribute__((ext_vector_type(4))) float f32x4;

static __device__ __forceinline__ short f2bf(float f) {
  __hip_bfloat16 h = __float2bfloat16(f);
  return __builtin_bit_cast(short, h);
}
static __device__ __forceinline__ float bf2f(short s) {
  return __bfloat162float(__builtin_bit_cast(__hip_bfloat16, s));
}
static __device__ __forceinline__ unsigned pk2(float a, float b) {
  unsigned lo = (unsigned short)f2bf(a);
  unsigned hi = (unsigned short)f2bf(b);
  return lo | (hi << 16);
}

static __device__ __forceinline__ void gld_lds16(const void* g, void* l) {
  __builtin_amdgcn_global_load_lds(
      (const __attribute__((address_space(1))) unsigned int*)g,
      (__attribute__((address_space(3))) unsigned int*)l, 16, 0, 0);
}

// DPP rotate-right within each 16-lane row
template<int N>
static __device__ __forceinline__ float dpp_ror(float x) {
  return __builtin_bit_cast(float, __builtin_amdgcn_update_dpp(
      0, __builtin_bit_cast(int, x), 0x120 + N, 0xF, 0xF, true));
}

// ---------------------------------------------------------------------------
// 1) f32 -> bf16 conversion for x, wq|wk|wv (packed), wo.  Unit = 4 floats.
__global__ __launch_bounds__(256) void cvt_all_kernel(
    const float* __restrict__ x, const float* __restrict__ wq,
    const float* __restrict__ wk, const float* __restrict__ wv,
    const float* __restrict__ wo,
    short* __restrict__ xb, short* __restrict__ wqkvb, short* __restrict__ wob) {
  size_t u = (size_t)blockIdx.x * 256 + threadIdx.x;
  const float* src; short* dst;
  if (u < 2097152)                   { src = x;  dst = xb; }
  else if ((u -= 2097152) < 262144)  { src = wq; dst = wqkvb; }
  else if ((u -= 262144) < 65536)    { src = wk; dst = wqkvb + 1024*1024; }
  else if ((u -= 65536) < 65536)     { src = wv; dst = wqkvb + 1280*1024; }
  else { u -= 65536;                   src = wo; dst = wob; }
  float4 v = ((const float4*)src)[u];
  short4 o;
  o.x = f2bf(v.x); o.y = f2bf(v.y); o.z = f2bf(v.z); o.w = f2bf(v.w);
  ((short4*)dst)[u] = o;
}

// ---------------------------------------------------------------------------
// 2) GEMM  C[M][N] = A[M][K] * B[N][K]^T   (bf16 in, bf16 or f32 out)
#define BMT 128
#define BNT 128
#define BKT 64

template<bool OUT_BF16>
__global__ __launch_bounds__(256) void gemm_bt(
    const short* __restrict__ A, const short* __restrict__ Bw,
    void* __restrict__ Cout, int M, int N, int K) {
  __shared__ __align__(16) short As[BMT*BKT];
  __shared__ __align__(16) short Bs[BNT*BKT];

  int nwg  = gridDim.x;
  int orig = blockIdx.x;
  int wg   = (orig & 7) * (nwg >> 3) + (orig >> 3);   // XCD swizzle (nwg%8==0)
  int tiles_n = N / BNT;
  int m0 = (wg / tiles_n) * BMT;
  int n0 = (wg % tiles_n) * BNT;

  int tid = threadIdx.x;
  int lane = tid & 63, wv = tid >> 6;
  int l15 = lane & 15, lg = lane >> 4;
  int wr = wv >> 1, wc = wv & 1;

  f32x4 acc[4][4] = {};

  for (int k0 = 0; k0 < K; k0 += BKT) {
    __syncthreads();
    const char* Abase = (const char*)(A + (size_t)m0 * K + k0);
    const char* Bbase = (const char*)(Bw + (size_t)n0 * K + k0);
#pragma unroll
    for (int i = 0; i < 4; ++i) {
      int idx = i * 256 + tid;
      int row = idx >> 3;
      int cb  = (idx & 7) << 4;
      int scb = cb ^ ((row & 7) << 4);
      gld_lds16(Abase + (size_t)row * (K * 2) + scb,
                (char*)As + ((i * 256 + wv * 64) << 4));
      gld_lds16(Bbase + (size_t)row * (K * 2) + scb,
                (char*)Bs + ((i * 256 + wv * 64) << 4));
    }
    __syncthreads();

#pragma unroll
    for (int kk = 0; kk < 2; ++kk) {
      short8 af[4], bfr[4];
      int kb = (kk * 32 + lg * 8) * 2;
#pragma unroll
      for (int mi = 0; mi < 4; ++mi) {
        int row = wr * 64 + mi * 16 + l15;
        af[mi] = *(const short8*)((const char*)As + row * 128 + (kb ^ ((row & 7) << 4)));
      }
#pragma unroll
      for (int ni = 0; ni < 4; ++ni) {
        int row = wc * 64 + ni * 16 + l15;
        bfr[ni] = *(const short8*)((const char*)Bs + row * 128 + (kb ^ ((row & 7) << 4)));
      }
#pragma unroll
      for (int mi = 0; mi < 4; ++mi)
#pragma unroll
        for (int ni = 0; ni < 4; ++ni)
          acc[mi][ni] = __builtin_amdgcn_mfma_f32_16x16x32_bf16(af[mi], bfr[ni], acc[mi][ni], 0, 0, 0);
    }
  }

  int crow0 = m0 + wr * 64, ccol0 = n0 + wc * 64;
#pragma unroll
  for (int mi = 0; mi < 4; ++mi)
#pragma unroll
    for (int ni = 0; ni < 4; ++ni)
#pragma unroll
      for (int r = 0; r < 4; ++r) {
        int row = crow0 + mi * 16 + lg * 4 + r;
        int col = ccol0 + ni * 16 + l15;
        float v = acc[mi][ni][r];
        if (OUT_BF16) ((short*)Cout)[(size_t)row * N + col] = f2bf(v);
        else          ((float*)Cout)[(size_t)row * N + col] = v;
      }
}

// ---------------------------------------------------------------------------
// 3) FUSED qk_norm + vtrans.  Blocks [0,10240): RMSNorm on q/k heads.
//    Blocks [10240,10752): V transpose qkv cols [1280..1536) -> Vt.
__global__ __launch_bounds__(256) void norm_vtrans_kernel(
    const short* __restrict__ qkv, const float* __restrict__ qw,
    const float* __restrict__ kw, short* __restrict__ Qh,
    short* __restrict__ Kh, short* __restrict__ Vt) {
  __shared__ short tile[64][72];
  if (blockIdx.x < 10240) {
    unsigned gid = blockIdx.x * 16u + (threadIdx.x >> 4);
    int l = threadIdx.x & 15;
    unsigned row = gid / 20u;          // b*T + t
    int s = (int)(gid - row * 20u);    // head slot 0..19
    int b = row >> 11, t = row & 2047;
    bool isq = s < 16;
    int col = isq ? s * 64 : 1024 + (s - 16) * 64;
    const short* rp = qkv + (size_t)row * NQKV + col + l * 4;
    short4 v4 = *(const short4*)rp;
    float f0 = bf2f(v4.x), f1 = bf2f(v4.y), f2 = bf2f(v4.z), f3 = bf2f(v4.w);
    float ss = f0 * f0 + f1 * f1 + f2 * f2 + f3 * f3;
    ss += dpp_ror<1>(ss); ss += dpp_ror<2>(ss);
    ss += dpp_ror<4>(ss); ss += dpp_ror<8>(ss);
    float r = rsqrtf(ss * (1.0f / 64.0f) + 1e-6f);
    float4 w4 = *(const float4*)((isq ? qw : kw) + l * 4);
    short4 o;
    o.x = f2bf(f0 * r * w4.x); o.y = f2bf(f1 * r * w4.y);
    o.z = f2bf(f2 * r * w4.z); o.w = f2bf(f3 * r * w4.w);
    if (isq) *(short4*)(Qh + (((size_t)b * NH + s) * TT + t) * HDIM + l * 4) = o;
    else     *(short4*)(Kh + (((size_t)b * NKV + (s - 16)) * TT + t) * HDIM + l * 4) = o;
  } else {
    int vi = blockIdx.x - 10240;
    int tb = vi & 31, kv = (vi >> 5) & 3, b = vi >> 7;
    int tid = threadIdx.x;
#pragma unroll
    for (int i = 0; i < 2; ++i) {
      int idx = i * 256 + tid;
      int tr = idx >> 3;
      int c8 = (idx & 7) * 8;
      int t = tb * 64 + tr;
      const short* src = qkv + (size_t)(b * TT + t) * NQKV + 1280 + kv * 64 + c8;
      short8 v = *(const short8*)src;
#pragma unroll
      for (int j = 0; j < 8; ++j) tile[tr][c8 + j] = v[j];
    }
    __syncthreads();
#pragma unroll
    for (int i = 0; i < 2; ++i) {
      int idx = i * 256 + tid;
      int d = idx >> 3;
      int t8 = (idx & 7) * 8;
      short8 o;
#pragma unroll
      for (int j = 0; j < 8; ++j) o[j] = tile[t8 + j][d];
      short* dst = Vt + (((size_t)(b * NKV + kv) * HDIM) + d) * TT + tb * 64 + t8;
      *(short8*)dst = o;
    }
  }
}

// ---------------------------------------------------------------------------
// 5) Sliding-window causal flash attention (GQA).  r18 structure (44us floor).
//    BLOCK = (b, kvh, qh): 4 waves = the 4 q-heads of one GQA group sharing
//    the same 32-q window.  BOTH K and V tiles (8KB each) staged per block
//    into LDS via global_load_lds (4 waves cooperative) with rule-21 XOR
//    swizzle (linear LDS dest, pre-swizzled global source, swizzled read).
//    Swapped QK^T (P[k][q] k-major/lane), fixed-max softmax.
//    r25: setprio REMOVED — T5 needs wave role diversity (m218b); our waves
//    are barrier-locked per tile (lockstep), where m190 measured setprio as
//    a small NEGATIVE.  A/B: zero correctness risk.
#define C1A 0.180336880f   // 0.125 * log2(e)
#define C2A 11.5415603f    // 8     * log2(e)

__global__ __launch_bounds__(256) void attn_kernel(
    const short* __restrict__ Qh, const short* __restrict__ Kh,
    const short* __restrict__ Vt, short* __restrict__ Y) {
  int wgid = blockIdx.x;
  int qh = wgid >> 4;                  // 0..63, SLOWEST (per-CU balance)
  int kvh = (wgid >> 2) & 3;
  int b = wgid & 3;
  int tid = threadIdx.x, lane = tid & 63, wv = tid >> 6;
  int l15 = lane & 15, lg = lane >> 4;
  int h = kvh * 4 + wv;                // this wave's q-head
  int q0 = qh * 32;
  const short* Qp = Qh + (((size_t)b * NH + h) * TT + q0) * HDIM;
  const char*  Kp = (const char*)(Kh + ((size_t)b * NKV + kvh) * TT * HDIM);
  const char*  Vp = (const char*)(Vt + ((size_t)b * NKV + kvh) * HDIM * TT);

  short8 aqA0 = *(const short8*)(Qp + l15 * HDIM + lg * 8);
  short8 aqA1 = *(const short8*)(Qp + l15 * HDIM + 32 + lg * 8);
  short8 aqB0 = *(const short8*)(Qp + (16 + l15) * HDIM + lg * 8);
  short8 aqB1 = *(const short8*)(Qp + (16 + l15) * HDIM + 32 + lg * 8);

  float lpA = 0.f, lpB = 0.f;          // lane-scalar partials (q = l15)
  f32x4 yA[4] = {}, yB[4] = {};

  // LDS: K 8192 + V 8192 + 4 x 4608 per-wave P scratch = 34816 B
  __shared__ __align__(16) char smem[34816];
  char* Kbuf = smem;
  char* Vbuf = smem + 8192;
  short* PA = (short*)(smem + 16384 + wv * 4608);
  short* PB = PA + 1152;

  int lo = q0 - (WINSZ - 1); if (lo < 0) lo = 0;
  int klo = lo & ~63;
  int nt = (q0 + 32 - klo + 63) >> 6;  // CEIL tile count

  int qiA = q0 + l15, qiB = qiA + 16;  // q index per lane (swapped layout)

  for (int t = 0; t < nt; ++t) {
    int kc = klo + t * 64;
    __syncthreads();                   // prior tile's LDS reads complete
    // ---- STAGE K and V tiles: wave wv stages rows wv*16..wv*16+15 of each
    //      (2 x 1KB per operand).  LDS dest linear; source pre-swizzled:
    //      LDS[rr][cb] = X[rr][cb ^ ((rr&7)<<4)]
#pragma unroll
    for (int r = 0; r < 2; ++r) {
      int rr = wv * 16 + r * 8 + (lane >> 3);
      int cb = (lane & 7) * 16;
      int scb = cb ^ ((rr & 7) << 4);
      gld_lds16(Kp + (size_t)(kc + rr) * 128 + scb,
                Kbuf + wv * 2048 + r * 1024);
      gld_lds16(Vp + (size_t)rr * (TT * 2) + kc * 2 + scb,
                Vbuf + wv * 2048 + r * 1024);
    }
    __syncthreads();                   // vmcnt(0) drain: staging complete

    int sw = (l15 & 7) << 4;
    // ---- K fragments from LDS (swizzled read: conflict-free)
    short8 bk0[4], bk1[4];
#pragma unroll
    for (int nc = 0; nc < 4; ++nc) {
      int rb = (nc * 16 + l15) * 128;
      bk0[nc] = *(const short8*)(Kbuf + rb + ((lg * 16) ^ sw));
      bk1[nc] = *(const short8*)(Kbuf + rb + ((lg * 16 + 64) ^ sw));
    }
    // ---- V fragments from LDS (same pattern)
    short8 bv0[4], bv1[4];
#pragma unroll
    for (int dt = 0; dt < 4; ++dt) {
      int rb = (dt * 16 + l15) * 128;
      bv0[dt] = *(const short8*)(Vbuf + rb + ((lg * 16) ^ sw));
      bv1[dt] = *(const short8*)(Vbuf + rb + ((lg * 16 + 64) ^ sw));
    }
    // ---- swapped QK^T: D[k][q]
    f32x4 sA[4], sB[4];
#pragma unroll
    for (int nc = 0; nc < 4; ++nc) {
      f32x4 zA = {}, zB = {};
      zA = __builtin_amdgcn_mfma_f32_16x16x32_bf16(bk0[nc], aqA0, zA, 0, 0, 0);
      zB = __builtin_amdgcn_mfma_f32_16x16x32_bf16(bk0[nc], aqB0, zB, 0, 0, 0);
      zA = __builtin_amdgcn_mfma_f32_16x16x32_bf16(bk1[nc], aqA1, zA, 0, 0, 0);
      zB = __builtin_amdgcn_mfma_f32_16x16x32_bf16(bk1[nc], aqB1, zB, 0, 0, 0);
      sA[nc] = zA; sB[nc] = zB;
    }
    // ---- fixed-max softmax, pack, vector LDS write (k-major per lane)
    bool intA = (kc >= q0 - 496) && (kc + 63 <= q0);
    bool intB = (kc >= q0 - 480) && (kc + 63 <= q0 + 16);
    if (intA && intB) {
#pragma unroll
      for (int nc = 0; nc < 4; ++nc) {
        float pa0 = __builtin_amdgcn_exp2f(fmaf(sA[nc][0], C1A, -C2A));
        float pa1 = __builtin_amdgcn_exp2f(fmaf(sA[nc][1], C1A, -C2A));
        float pa2 = __builtin_amdgcn_exp2f(fmaf(sA[nc][2], C1A, -C2A));
        float pa3 = __builtin_amdgcn_exp2f(fmaf(sA[nc][3], C1A, -C2A));
        float pb0 = __builtin_amdgcn_exp2f(fmaf(sB[nc][0], C1A, -C2A));
        float pb1 = __builtin_amdgcn_exp2f(fmaf(sB[nc][1], C1A, -C2A));
        float pb2 = __builtin_amdgcn_exp2f(fmaf(sB[nc][2], C1A, -C2A));
        float pb3 = __builtin_amdgcn_exp2f(fmaf(sB[nc][3], C1A, -C2A));
        lpA += (pa0 + pa1) + (pa2 + pa3);
        lpB += (pb0 + pb1) + (pb2 + pb3);
        *(uint2*)(PA + l15 * 72 + nc * 16 + lg * 4) = uint2{pk2(pa0, pa1), pk2(pa2, pa3)};
        *(uint2*)(PB + l15 * 72 + nc * 16 + lg * 4) = uint2{pk2(pb0, pb1), pk2(pb2, pb3)};
      }
    } else {
      int kjb = kc + lg * 4;
#pragma unroll
      for (int nc = 0; nc < 4; ++nc) {
        float pa[4], pb[4];
#pragma unroll
        for (int r = 0; r < 4; ++r) {
          int kj = kjb + nc * 16 + r;
          bool okA = (kj <= qiA) && (qiA - kj < WINSZ);
          bool okB = (kj <= qiB) && (qiB - kj < WINSZ);
          pa[r] = okA ? __builtin_amdgcn_exp2f(fmaf(sA[nc][r], C1A, -C2A)) : 0.f;
          pb[r] = okB ? __builtin_amdgcn_exp2f(fmaf(sB[nc][r], C1A, -C2A)) : 0.f;
        }
        lpA += (pa[0] + pa[1]) + (pa[2] + pa[3]);
        lpB += (pb[0] + pb[1]) + (pb[2] + pb[3]);
        *(uint2*)(PA + l15 * 72 + nc * 16 + lg * 4) = uint2{pk2(pa[0], pa[1]), pk2(pa[2], pa[3])};
        *(uint2*)(PB + l15 * 72 + nc * 16 + lg * 4) = uint2{pk2(pb[0], pb[1]), pk2(pb[2], pb[3])};
      }
    }
    // ---- PV A-fragments (per-wave LDS region, no barrier)
    short8 apA0 = *(const short8*)(PA + l15 * 72 + lg * 8);
    short8 apA1 = *(const short8*)(PA + l15 * 72 + 32 + lg * 8);
    short8 apB0 = *(const short8*)(PB + l15 * 72 + lg * 8);
    short8 apB1 = *(const short8*)(PB + l15 * 72 + 32 + lg * 8);
#pragma unroll
    for (int dt = 0; dt < 4; ++dt) {
      yA[dt] = __builtin_amdgcn_mfma_f32_16x16x32_bf16(apA0, bv0[dt], yA[dt], 0, 0, 0);
      yB[dt] = __builtin_amdgcn_mfma_f32_16x16x32_bf16(apB0, bv0[dt], yB[dt], 0, 0, 0);
      yA[dt] = __builtin_amdgcn_mfma_f32_16x16x32_bf16(apA1, bv1[dt], yA[dt], 0, 0, 0);
      yB[dt] = __builtin_amdgcn_mfma_f32_16x16x32_bf16(apB1, bv1[dt], yB[dt], 0, 0, 0);
    }
  }

  // ---- per-wave epilogue (wave owns its head completely; no combine)
  lpA += __shfl_xor(lpA, 16); lpA += __shfl_xor(lpA, 32);
  lpB += __shfl_xor(lpB, 16); lpB += __shfl_xor(lpB, 32);
  float invqA = 1.0f / lpA;            // q = l15
  float invqB = 1.0f / lpB;
#pragma unroll
  for (int r = 0; r < 4; ++r) {
    // redistribute: y rows are q = lg*4+r -> pull inv from lane (lg*4+r)
    float invA = __builtin_bit_cast(float, __builtin_amdgcn_ds_bpermute(
        (lg * 4 + r) << 2, __builtin_bit_cast(int, invqA)));
    float invB = __builtin_bit_cast(float, __builtin_amdgcn_ds_bpermute(
        (lg * 4 + r) << 2, __builtin_bit_cast(int, invqB)));
    int qiAo = q0 + lg * 4 + r, qiBo = qiAo + 16;
#pragma unroll
    for (int dt = 0; dt < 4; ++dt) {
      Y[((size_t)(b * TT + qiAo)) * DIMD + h * HDIM + dt * 16 + l15] = f2bf(yA[dt][r] * invA);
      Y[((size_t)(b * TT + qiBo)) * DIMD + h * HDIM + dt * 16 + l15] = f2bf(yB[dt][r] * invB);
    }
  }
}

// ---------------------------------------------------------------------------
extern "C" void kernel_launch(void* const* d_in, const int* in_sizes, int n_in,
                              void* d_out, int out_size, void* d_ws, size_t ws_size,
                              hipStream_t stream) {
  const float* x  = (const float*)d_in[0];
  const float* wq = (const float*)d_in[1];
  const float* wk = (const float*)d_in[2];
  const float* wv = (const float*)d_in[3];
  const float* wo = (const float*)d_in[4];
  const float* qw = (const float*)d_in[5];
  const float* kw = (const float*)d_in[6];

  char* ws = (char*)d_ws;
  short* xb    = (short*)(ws + 0);            // 16 MB  [8192][1024] bf16
  short* wqkvb = (short*)(ws + 16777216);     // 3 MB   [1536][1024]
  short* wob   = (short*)(ws + 19922944);     // 2 MB   [1024][1024]
  short* qkv   = (short*)(ws + 22020096);     // 24 MB  [8192][1536]
  short* Qh    = (short*)(ws + 47185920);     // 16 MB  [B][H][T][64]
  short* Kh    = (short*)(ws + 63963136);     // 4 MB   [B][KV][T][64]
  short* Vt    = (short*)(ws + 68157440);     // 4 MB   [B][KV][64][T]
  short* Y     = xb;                          // alias: xb dead after QKV GEMM
  float* outp  = (float*)d_out;

  cvt_all_kernel<<<10752, 256, 0, stream>>>(x, wq, wk, wv, wo, xb, wqkvb, wob);
  gemm_bt<true><<<dim3(64 * 12), 256, 0, stream>>>(xb, wqkvb, (void*)qkv, MROWS, NQKV, DIMD);
  norm_vtrans_kernel<<<10752, 256, 0, stream>>>(qkv, qw, kw, Qh, Kh, Vt);
  attn_kernel<<<1024, 256, 0, stream>>>(Qh, Kh, Vt, Y);
  gemm_bt<false><<<dim3(64 * 8), 256, 0, stream>>>(Y, wob, (void*)outp, MROWS, DIMD, DIMD);
}